// Round 4
// baseline (133.571 us; speedup 1.0000x reference)
//
#include <hip/hip_runtime.h>
#include <math.h>

#define DIM 64
#define HEADS 4
#define BB 8
#define QQ 128
#define VV 128
#define NN (BB*QQ)   // 1024

// DPP quad_perm(1,0,3,2): swap adjacent lanes (xor 1). VALU, no DS.
__device__ __forceinline__ float dpp_swap1(float x) {
    return __int_as_float(__builtin_amdgcn_update_dpp(
        0, __float_as_int(x), 0xB1, 0xF, 0xF, true));
}
// wave_shr:1 — lane j gets lane j-1 (lane 0 -> 0 via bound_ctrl). VALU, no DS.
__device__ __forceinline__ float dpp_wshr1(float x) {
    return __int_as_float(__builtin_amdgcn_update_dpp(
        0, __float_as_int(x), 0x138, 0xF, 0xF, true));
}
// wave_shl:1 — lane j gets lane j+1 (lane 63 -> 0 via bound_ctrl). VALU, no DS.
__device__ __forceinline__ float dpp_wshl1(float x) {
    return __int_as_float(__builtin_amdgcn_update_dpp(
        0, __float_as_int(x), 0x130, 0xF, 0xF, true));
}

// K1: Av[h][b*128+v][j] = (re,im) of sum_i values[b,v,i] * U[h, 64+i, j]
// values row address is wave-uniform (readfirstlane) -> s_load, no bpermute.
__global__ __launch_bounds__(256) void k_av(const float* __restrict__ values,
                                            const float* __restrict__ U_re,
                                            const float* __restrict__ U_im,
                                            float2* __restrict__ Av) {
    int tid = blockIdx.x * blockDim.x + threadIdx.x;
    int w = tid >> 6;          // 0..4095  (h, b*128+v)
    int j = tid & 63;
    int h = __builtin_amdgcn_readfirstlane(w >> 10);
    int rem = __builtin_amdgcn_readfirstlane(w & 1023);   // b*128 + v
    const float* vrow = values + rem * DIM;               // uniform base
    const float* ur = U_re + (h * 2 * DIM + DIM) * DIM + j;
    const float* ui = U_im + (h * 2 * DIM + DIM) * DIM + j;
    float ar = 0.f, ai = 0.f;
    #pragma unroll 16
    for (int i = 0; i < DIM; ++i) {
        float vi = vrow[i];                                // s_load (uniform)
        ar = fmaf(vi, ur[i * DIM], ar);
        ai = fmaf(vi, ui[i * DIM], ai);
    }
    Av[(h * 1024 + rem) * DIM + j] = make_float2(ar, ai);
}

// K2: block = (b, q): 4 waves = 4 heads; each wave scans TWO rows (q, q+64).
// Scan loop has ZERO DS ops and ZERO control flow: layer-2 parity selection is
// folded into per-lane coefficients BL (odd lanes) / BR (even lanes).
__global__ __launch_bounds__(256) void k_rnn_dense(
        const float* __restrict__ queries,
        const float* __restrict__ U_re,
        const float* __restrict__ U_im,
        const float* __restrict__ bias,
        const float* __restrict__ theta1,
        const float* __restrict__ phi1,
        const float* __restrict__ theta2,
        const float* __restrict__ phi2,
        const float* __restrict__ omega,
        const float2* __restrict__ Av,
        const float* __restrict__ W_dense,
        const float* __restrict__ b_dense,
        float* __restrict__ y) {
    int b = blockIdx.x >> 6;   // 0..7
    int q = blockIdx.x & 63;   // 0..63
    int t = threadIdx.x;
    int h = t >> 6;            // head = wave
    int j = t & 63;            // state dim = lane
    int n0 = b * 128 + q;      // row A (block-uniform)
    int n1 = n0 + 64;          // row B

    // ---- layer-1 coefficients: out = A1*self + B1*partner(xor 1) ----
    int k1 = j >> 1;
    float th1 = theta1[h * 32 + k1], ph1 = phi1[h * 32 + k1];
    float c1 = cosf(th1), s1 = sinf(th1);
    float A1r, A1i, B1r, B1i;
    if ((j & 1) == 0) {        // 'a': e1*(c1*a - s1*b)
        float er = cosf(ph1), ei = sinf(ph1);
        A1r = er * c1; A1i = ei * c1;
        B1r = -er * s1; B1i = -ei * s1;
    } else {                   // 'b': s1*a + c1*b
        A1r = c1; A1i = 0.f;
        B1r = s1; B1i = 0.f;
    }

    // ---- layer-2 (+omega folded): s = A2*t + BL*t[j+1] + BR*t[j-1] ----
    // odd interior j ('a'): partner j+1, coef -e2*s2 -> BL;  BR = 0
    // even interior j ('b'): partner j-1, coef s2      -> BR;  BL = 0
    // endpoints: A2 = 1, BL = BR = 0 (then omega phase folded into all)
    float A2r, A2i, BLr, BLi, BRr, BRi;
    if (j == 0 || j == 63) {
        A2r = 1.f; A2i = 0.f; BLr = 0.f; BLi = 0.f; BRr = 0.f; BRi = 0.f;
    } else {
        int k2 = (j - 1) >> 1;
        float th2 = theta2[h * 31 + k2], ph2 = phi2[h * 31 + k2];
        float c2 = cosf(th2), s2 = sinf(th2);
        if (j & 1) {           // odd = 'a': e2*(c2*self - s2*next)
            float er = cosf(ph2), ei = sinf(ph2);
            A2r = er * c2; A2i = ei * c2;
            BLr = -er * s2; BLi = -ei * s2;
            BRr = 0.f; BRi = 0.f;
        } else {               // even = 'b': s2*prev + c2*self
            A2r = c2; A2i = 0.f;
            BRr = s2; BRi = 0.f;
            BLr = 0.f; BLi = 0.f;
        }
    }
    {   // fold exp(i*omega) into A2, BL, BR
        float om = omega[h * 64 + j];
        float eor = cosf(om), eoi = sinf(om);
        float tr, ti;
        tr = A2r * eor - A2i * eoi; ti = A2r * eoi + A2i * eor; A2r = tr; A2i = ti;
        tr = BLr * eor - BLi * eoi; ti = BLr * eoi + BLi * eor; BLr = tr; BLi = ti;
        tr = BRr * eor - BRi * eoi; ti = BRr * eoi + BRi * eor; BRr = tr; BRi = ti;
    }
    float bj = bias[h * 64 + j];

    // ---- Aq for both rows; query rows are block-uniform -> s_load ----
    const float* qrow0 = queries + n0 * DIM;
    const float* qrow1 = queries + n1 * DIM;
    const float* ur = U_re + (h * 2 * DIM) * DIM + j;
    const float* ui = U_im + (h * 2 * DIM) * DIM + j;
    float uq0r = 0.f, uq0i = 0.f, uq1r = 0.f, uq1i = 0.f;
    #pragma unroll 16
    for (int i = 0; i < DIM; ++i) {
        float a0 = qrow0[i];               // s_load (uniform)
        float a1 = qrow1[i];               // s_load (uniform)
        float wr = ur[i * DIM], wi = ui[i * DIM];
        uq0r = fmaf(a0, wr, uq0r); uq0i = fmaf(a0, wi, uq0i);
        uq1r = fmaf(a1, wr, uq1r); uq1i = fmaf(a1, wi, uq1i);
    }

    const float2* Avp = Av + (h * 1024 + b * 128) * DIM + j;

    float h0r = 0.f, h0i = 0.f, h1r = 0.f, h1i = 0.f;
    #pragma unroll 4
    for (int v = 0; v < VV; ++v) {
        float2 av = Avp[v * DIM];            // shared by both rows
        // ---- row 0 ----
        {
            float pr = dpp_swap1(h0r), pi = dpp_swap1(h0i);
            float t_r = A1r * h0r - A1i * h0i + B1r * pr - B1i * pi;
            float t_i = A1r * h0i + A1i * h0r + B1r * pi + B1i * pr;
            float Lr = dpp_wshl1(t_r), Li = dpp_wshl1(t_i);
            float Rr = dpp_wshr1(t_r), Ri = dpp_wshr1(t_i);
            float s_r = A2r * t_r - A2i * t_i + BLr * Lr - BLi * Li + BRr * Rr - BRi * Ri;
            float s_i = A2r * t_i + A2i * t_r + BLr * Li + BLi * Lr + BRr * Ri + BRi * Rr;
            float zr = s_r + uq0r + av.x;
            float zi = s_i + uq0i + av.y;
            float q2 = fmaf(zr, zr, fmaf(zi, zi, 1e-30f));
            float rs = __builtin_amdgcn_rsqf(q2);
            float m = q2 * rs;
            float sc = fmaxf(m + bj, 0.f) * __builtin_amdgcn_rcpf(m + 1e-5f);
            h0r = zr * sc; h0i = zi * sc;
        }
        // ---- row 1 (independent chain, same coefs) ----
        {
            float pr = dpp_swap1(h1r), pi = dpp_swap1(h1i);
            float t_r = A1r * h1r - A1i * h1i + B1r * pr - B1i * pi;
            float t_i = A1r * h1i + A1i * h1r + B1r * pi + B1i * pr;
            float Lr = dpp_wshl1(t_r), Li = dpp_wshl1(t_i);
            float Rr = dpp_wshr1(t_r), Ri = dpp_wshr1(t_i);
            float s_r = A2r * t_r - A2i * t_i + BLr * Lr - BLi * Li + BRr * Rr - BRi * Ri;
            float s_i = A2r * t_i + A2i * t_r + BLr * Li + BLi * Lr + BRr * Ri + BRi * Rr;
            float zr = s_r + uq1r + av.x;
            float zi = s_i + uq1i + av.y;
            float q2 = fmaf(zr, zr, fmaf(zi, zi, 1e-30f));
            float rs = __builtin_amdgcn_rsqf(q2);
            float m = q2 * rs;
            float sc = fmaxf(m + bj, 0.f) * __builtin_amdgcn_rcpf(m + 1e-5f);
            h1r = zr * sc; h1i = zi * sc;
        }
    }

    // ---- fused dense for rows n0, n1 ----
    __shared__ float s_acc[2][HEADS * DIM];   // 2 x 256
    __shared__ float s_part[256];
    s_acc[0][h * 64 + j] = h0r;
    s_acc[1][h * 64 + j] = h1r;
    __syncthreads();

    {   // thread t: row r = t>>7, k-half hf = (t>>6)&1, col jj = t&63
        int r = t >> 7, hf = (t >> 6) & 1, jj = t & 63;
        const float* Wp = W_dense + (hf * 128) * DIM + jj;
        const float* ap = &s_acc[r][hf * 128];
        float part = 0.f;
        #pragma unroll 8
        for (int k = 0; k < 128; ++k)
            part = fmaf(ap[k], Wp[k * DIM], part);   // ap broadcast, Wp coalesced
        s_part[t] = part;
    }
    __syncthreads();
    if (t < 128) {
        int r = t >> 6, jj = t & 63;
        y[(n0 + r * 64) * DIM + jj] =
            b_dense[jj] + s_part[r * 128 + jj] + s_part[r * 128 + 64 + jj];
    }
}

extern "C" void kernel_launch(void* const* d_in, const int* in_sizes, int n_in,
                              void* d_out, int out_size, void* d_ws, size_t ws_size,
                              hipStream_t stream) {
    const float* queries = (const float*)d_in[0];
    const float* values  = (const float*)d_in[1];
    const float* U_re    = (const float*)d_in[2];
    const float* U_im    = (const float*)d_in[3];
    const float* bias    = (const float*)d_in[4];
    const float* theta1  = (const float*)d_in[5];
    const float* phi1    = (const float*)d_in[6];
    const float* theta2  = (const float*)d_in[7];
    const float* phi2    = (const float*)d_in[8];
    const float* omega   = (const float*)d_in[9];
    const float* W_dense = (const float*)d_in[10];
    const float* b_dense = (const float*)d_in[11];
    float* y = (float*)d_out;

    float2* Av = (float2*)d_ws;   // HEADS*BB*VV*DIM float2 = 2 MB

    k_av<<<1024, 256, 0, stream>>>(values, U_re, U_im, Av);
    k_rnn_dense<<<512, 256, 0, stream>>>(queries, U_re, U_im, bias, theta1,
                                         phi1, theta2, phi2, omega, Av,
                                         W_dense, b_dense, y);
}

// Round 5
// 119.999 us; speedup vs baseline: 1.1131x; 1.1131x over previous
//
#include <hip/hip_runtime.h>
#include <math.h>

#define DIM 64
#define HEADS 4
#define BB 8
#define QQ 128
#define VV 128
#define NN (BB*QQ)   // 1024

typedef float f2 __attribute__((ext_vector_type(2)));

// DPP quad_perm(1,0,3,2): swap adjacent lanes (xor 1). VALU, no DS.
__device__ __forceinline__ float dpp_swap1(float x) {
    return __int_as_float(__builtin_amdgcn_update_dpp(
        0, __float_as_int(x), 0xB1, 0xF, 0xF, true));
}
// wave_shr:1 — lane j gets lane j-1 (lane 0 -> 0 via bound_ctrl). VALU, no DS.
__device__ __forceinline__ float dpp_wshr1(float x) {
    return __int_as_float(__builtin_amdgcn_update_dpp(
        0, __float_as_int(x), 0x138, 0xF, 0xF, true));
}
// wave_shl:1 — lane j gets lane j+1 (lane 63 -> 0 via bound_ctrl). VALU, no DS.
__device__ __forceinline__ float dpp_wshl1(float x) {
    return __int_as_float(__builtin_amdgcn_update_dpp(
        0, __float_as_int(x), 0x130, 0xF, 0xF, true));
}
__device__ __forceinline__ f2 dpp2_swap1(f2 x) {
    f2 r; r.x = dpp_swap1(x.x); r.y = dpp_swap1(x.y); return r;
}
__device__ __forceinline__ f2 dpp2_shl1(f2 x) {
    f2 r; r.x = dpp_wshl1(x.x); r.y = dpp_wshl1(x.y); return r;
}
__device__ __forceinline__ f2 dpp2_shr1(f2 x) {
    f2 r; r.x = dpp_wshr1(x.x); r.y = dpp_wshr1(x.y); return r;
}

// K1: Av[h][row][j] = (re,im) of sum_i values[row,i] * U[h, 64+i, j]
// 4 rows per wave: U loads amortized 4x; (re,im) packed -> v_pk_fma_f32.
__global__ __launch_bounds__(256) void k_av(const float* __restrict__ values,
                                            const float* __restrict__ U_re,
                                            const float* __restrict__ U_im,
                                            f2* __restrict__ Av) {
    int tid = blockIdx.x * blockDim.x + threadIdx.x;
    int w = tid >> 6;            // 0..1023
    int j = tid & 63;
    int h = w >> 8;              // 0..3
    int r0 = (w & 255) << 2;     // first of 4 rows within head h (0..1020)
    const float* vrow = values + r0 * DIM;                     // wave-uniform
    const float* ur = U_re + (h * 2 * DIM + DIM) * DIM + j;    // bottom half
    const float* ui = U_im + (h * 2 * DIM + DIM) * DIM + j;
    f2 a0 = 0.f, a1 = 0.f, a2 = 0.f, a3 = 0.f;
    #pragma unroll 8
    for (int i = 0; i < DIM; ++i) {
        f2 u; u.x = ur[i * DIM]; u.y = ui[i * DIM];
        a0 += vrow[i] * u;                 // s_load scalars broadcast
        a1 += vrow[DIM + i] * u;
        a2 += vrow[2 * DIM + i] * u;
        a3 += vrow[3 * DIM + i] * u;
    }
    f2* out = Av + (h * 1024 + r0) * DIM + j;
    out[0] = a0; out[DIM] = a1; out[2 * DIM] = a2; out[3 * DIM] = a3;
}

// K2: block = (b, q): 4 waves = 4 heads; each wave scans TWO rows (q, q+64),
// states packed as f2 (component = row) -> v_pk_fma_f32. No DS, no branches
// in the scan; Av software-prefetched one step ahead.
__global__ __launch_bounds__(256) void k_rnn_dense(
        const float* __restrict__ queries,
        const float* __restrict__ U_re,
        const float* __restrict__ U_im,
        const float* __restrict__ bias,
        const float* __restrict__ theta1,
        const float* __restrict__ phi1,
        const float* __restrict__ theta2,
        const float* __restrict__ phi2,
        const float* __restrict__ omega,
        const f2* __restrict__ Av,
        const float* __restrict__ W_dense,
        const float* __restrict__ b_dense,
        float* __restrict__ y) {
    int b = blockIdx.x >> 6;   // 0..7
    int q = blockIdx.x & 63;   // 0..63
    int t = threadIdx.x;
    int h = t >> 6;            // head = wave
    int j = t & 63;            // state dim = lane
    int n0 = b * 128 + q;      // row A (block-uniform)
    int n1 = n0 + 64;          // row B

    // ---- layer-1 coefficients: out = A1*self + B1*partner(xor 1) ----
    int k1 = j >> 1;
    float th1 = theta1[h * 32 + k1], ph1 = phi1[h * 32 + k1];
    float c1 = cosf(th1), s1 = sinf(th1);
    float A1r, A1i, B1r, B1i;
    if ((j & 1) == 0) {        // 'a': e1*(c1*a - s1*b)
        float er = cosf(ph1), ei = sinf(ph1);
        A1r = er * c1; A1i = ei * c1;
        B1r = -er * s1; B1i = -ei * s1;
    } else {                   // 'b': s1*a + c1*b
        A1r = c1; A1i = 0.f;
        B1r = s1; B1i = 0.f;
    }

    // ---- layer-2 (+omega): s = A2*t + BL*t[j+1] + BR*t[j-1], parity-folded ----
    float A2r, A2i, BLr, BLi, BRr, BRi;
    if (j == 0 || j == 63) {
        A2r = 1.f; A2i = 0.f; BLr = 0.f; BLi = 0.f; BRr = 0.f; BRi = 0.f;
    } else {
        int k2 = (j - 1) >> 1;
        float th2 = theta2[h * 31 + k2], ph2 = phi2[h * 31 + k2];
        float c2 = cosf(th2), s2 = sinf(th2);
        if (j & 1) {           // odd = 'a': e2*(c2*self - s2*next)
            float er = cosf(ph2), ei = sinf(ph2);
            A2r = er * c2; A2i = ei * c2;
            BLr = -er * s2; BLi = -ei * s2;
            BRr = 0.f; BRi = 0.f;
        } else {               // even = 'b': s2*prev + c2*self
            A2r = c2; A2i = 0.f;
            BRr = s2; BRi = 0.f;
            BLr = 0.f; BLi = 0.f;
        }
    }
    {   // fold exp(i*omega) into A2, BL, BR
        float om = omega[h * 64 + j];
        float eor = cosf(om), eoi = sinf(om);
        float tr, ti;
        tr = A2r * eor - A2i * eoi; ti = A2r * eoi + A2i * eor; A2r = tr; A2i = ti;
        tr = BLr * eor - BLi * eoi; ti = BLr * eoi + BLi * eor; BLr = tr; BLi = ti;
        tr = BRr * eor - BRi * eoi; ti = BRr * eoi + BRi * eor; BRr = tr; BRi = ti;
    }
    float bj = bias[h * 64 + j];

    // ---- Aq for both rows (packed); query rows block-uniform -> s_load ----
    const float* qrow0 = queries + n0 * DIM;
    const float* qrow1 = queries + n1 * DIM;
    const float* ur = U_re + (h * 2 * DIM) * DIM + j;
    const float* ui = U_im + (h * 2 * DIM) * DIM + j;
    f2 Uqr = 0.f, Uqi = 0.f;   // component 0 = row n0, 1 = row n1
    #pragma unroll 8
    for (int i = 0; i < DIM; ++i) {
        f2 a; a.x = qrow0[i]; a.y = qrow1[i];
        float wr = ur[i * DIM], wi = ui[i * DIM];
        Uqr += a * wr;
        Uqi += a * wi;
    }

    const f2* Avp = Av + (h * 1024 + b * 128) * DIM + j;

    f2 Hr = 0.f, Hi = 0.f;
    f2 av = Avp[0];
    #pragma unroll 4
    for (int v = 0; v < VV; ++v) {
        f2 avn = Avp[((v + 1) & 127) * DIM];   // prefetch next (wrap: unused)
        // layer 1
        f2 Pr = dpp2_swap1(Hr), Pi = dpp2_swap1(Hi);
        f2 Tr = A1r * Hr - A1i * Hi + B1r * Pr - B1i * Pi;
        f2 Ti = A1r * Hi + A1i * Hr + B1r * Pi + B1i * Pr;
        // layer 2 (+omega)
        f2 Lr = dpp2_shl1(Tr), Li = dpp2_shl1(Ti);
        f2 Rr = dpp2_shr1(Tr), Ri = dpp2_shr1(Ti);
        f2 Sr = A2r * Tr - A2i * Ti + BLr * Lr - BLi * Li + BRr * Rr - BRi * Ri;
        f2 Si = A2r * Ti + A2i * Tr + BLr * Li + BLi * Lr + BRr * Ri + BRi * Rr;
        // input: u = Aq + Av[v] (av components are re/im, same for both rows)
        f2 Zr = Sr + Uqr + av.x;
        f2 Zi = Si + Uqi + av.y;
        // modrelu
        f2 q2 = Zr * Zr + Zi * Zi + 1e-30f;
        f2 rs; rs.x = __builtin_amdgcn_rsqf(q2.x); rs.y = __builtin_amdgcn_rsqf(q2.y);
        f2 m = q2 * rs;
        f2 tp = m + bj;
        tp.x = fmaxf(tp.x, 0.f); tp.y = fmaxf(tp.y, 0.f);
        f2 mi = m + 1e-5f;
        f2 inv; inv.x = __builtin_amdgcn_rcpf(mi.x); inv.y = __builtin_amdgcn_rcpf(mi.y);
        f2 sc = tp * inv;
        Hr = Zr * sc; Hi = Zi * sc;
        av = avn;
    }

    // ---- fused dense for rows n0, n1 ----
    __shared__ float s_acc[2][HEADS * DIM];   // 2 x 256
    __shared__ float s_part[256];
    s_acc[0][h * 64 + j] = Hr.x;
    s_acc[1][h * 64 + j] = Hr.y;
    __syncthreads();

    {   // thread t: row r = t>>7, k-half hf = (t>>6)&1, col jj = t&63
        int r = t >> 7, hf = (t >> 6) & 1, jj = t & 63;
        const float* Wp = W_dense + (hf * 128) * DIM + jj;
        const float* ap = &s_acc[r][hf * 128];
        float part = 0.f;
        #pragma unroll 8
        for (int k = 0; k < 128; ++k)
            part = fmaf(ap[k], Wp[k * DIM], part);   // ap broadcast, Wp coalesced
        s_part[t] = part;
    }
    __syncthreads();
    if (t < 128) {
        int r = t >> 6, jj = t & 63;
        y[(n0 + r * 64) * DIM + jj] =
            b_dense[jj] + s_part[r * 128 + jj] + s_part[r * 128 + 64 + jj];
    }
}

extern "C" void kernel_launch(void* const* d_in, const int* in_sizes, int n_in,
                              void* d_out, int out_size, void* d_ws, size_t ws_size,
                              hipStream_t stream) {
    const float* queries = (const float*)d_in[0];
    const float* values  = (const float*)d_in[1];
    const float* U_re    = (const float*)d_in[2];
    const float* U_im    = (const float*)d_in[3];
    const float* bias    = (const float*)d_in[4];
    const float* theta1  = (const float*)d_in[5];
    const float* phi1    = (const float*)d_in[6];
    const float* theta2  = (const float*)d_in[7];
    const float* phi2    = (const float*)d_in[8];
    const float* omega   = (const float*)d_in[9];
    const float* W_dense = (const float*)d_in[10];
    const float* b_dense = (const float*)d_in[11];
    float* y = (float*)d_out;

    f2* Av = (f2*)d_ws;   // HEADS*1024*64 f2 = 2 MB

    k_av<<<256, 256, 0, stream>>>(values, U_re, U_im, Av);
    k_rnn_dense<<<512, 256, 0, stream>>>(queries, U_re, U_im, bias, theta1,
                                         phi1, theta2, phi2, omega, Av,
                                         W_dense, b_dense, y);
}

// Round 6
// 118.100 us; speedup vs baseline: 1.1310x; 1.0161x over previous
//
#include <hip/hip_runtime.h>
#include <math.h>

#define DIM 64
#define HEADS 4
#define BB 8
#define QQ 128
#define VV 128
#define NN (BB*QQ)   // 1024

typedef float f2 __attribute__((ext_vector_type(2)));

// DPP quad_perm(1,0,3,2): swap adjacent lanes (xor 1). VALU, no DS.
__device__ __forceinline__ float dpp_swap1(float x) {
    return __int_as_float(__builtin_amdgcn_update_dpp(
        0, __float_as_int(x), 0xB1, 0xF, 0xF, true));
}
// wave_shr:1 — lane j gets lane j-1 (lane 0 -> 0 via bound_ctrl). VALU, no DS.
__device__ __forceinline__ float dpp_wshr1(float x) {
    return __int_as_float(__builtin_amdgcn_update_dpp(
        0, __float_as_int(x), 0x138, 0xF, 0xF, true));
}
// wave_shl:1 — lane j gets lane j+1 (lane 63 -> 0 via bound_ctrl). VALU, no DS.
__device__ __forceinline__ float dpp_wshl1(float x) {
    return __int_as_float(__builtin_amdgcn_update_dpp(
        0, __float_as_int(x), 0x130, 0xF, 0xF, true));
}
__device__ __forceinline__ f2 dpp2_swap1(f2 x) {
    f2 r; r.x = dpp_swap1(x.x); r.y = dpp_swap1(x.y); return r;
}
__device__ __forceinline__ f2 dpp2_shl1(f2 x) {
    f2 r; r.x = dpp_wshl1(x.x); r.y = dpp_wshl1(x.y); return r;
}
__device__ __forceinline__ f2 dpp2_shr1(f2 x) {
    f2 r; r.x = dpp_wshr1(x.x); r.y = dpp_wshr1(x.y); return r;
}

// K1: Av[h][row][j] = (re,im) of sum_i values[row,i] * U[h, 64+i, j]
__global__ __launch_bounds__(256) void k_av(const float* __restrict__ values,
                                            const float* __restrict__ U_re,
                                            const float* __restrict__ U_im,
                                            f2* __restrict__ Av) {
    int tid = blockIdx.x * blockDim.x + threadIdx.x;
    int w = tid >> 6;            // 0..1023
    int j = tid & 63;
    int h = w >> 8;              // 0..3
    int r0 = (w & 255) << 2;     // first of 4 rows within head h (0..1020)
    const float* vrow = values + r0 * DIM;                     // wave-uniform
    const float* ur = U_re + (h * 2 * DIM + DIM) * DIM + j;    // bottom half
    const float* ui = U_im + (h * 2 * DIM + DIM) * DIM + j;
    f2 a0 = 0.f, a1 = 0.f, a2 = 0.f, a3 = 0.f;
    #pragma unroll 8
    for (int i = 0; i < DIM; ++i) {
        f2 u; u.x = ur[i * DIM]; u.y = ui[i * DIM];
        a0 += vrow[i] * u;                 // s_load scalars broadcast
        a1 += vrow[DIM + i] * u;
        a2 += vrow[2 * DIM + i] * u;
        a3 += vrow[3 * DIM + i] * u;
    }
    f2* out = Av + (h * 1024 + r0) * DIM + j;
    out[0] = a0; out[DIM] = a1; out[2 * DIM] = a2; out[3 * DIM] = a3;
}

// K2: block = (b, q): 4 waves = 4 heads; each wave scans TWO rows (q, q+64),
// states packed as f2 (component = row). No DS, no branches in the scan.
// Modrelu uses the identity 1/m == rsq(q2) (m = q2*rsq(q2)) — no v_rcp.
__global__ __launch_bounds__(256) void k_rnn_dense(
        const float* __restrict__ queries,
        const float* __restrict__ U_re,
        const float* __restrict__ U_im,
        const float* __restrict__ bias,
        const float* __restrict__ theta1,
        const float* __restrict__ phi1,
        const float* __restrict__ theta2,
        const float* __restrict__ phi2,
        const float* __restrict__ omega,
        const f2* __restrict__ Av,
        const float* __restrict__ W_dense,
        const float* __restrict__ b_dense,
        float* __restrict__ y) {
    int b = blockIdx.x >> 6;   // 0..7
    int q = blockIdx.x & 63;   // 0..63
    int t = threadIdx.x;
    int h = t >> 6;            // head = wave
    int j = t & 63;            // state dim = lane
    int n0 = b * 128 + q;      // row A (block-uniform)
    int n1 = n0 + 64;          // row B

    // ---- layer-1 coefficients: out = A1*self + B1*partner(xor 1) ----
    int k1 = j >> 1;
    float th1 = theta1[h * 32 + k1], ph1 = phi1[h * 32 + k1];
    float c1 = cosf(th1), s1 = sinf(th1);
    float A1r, A1i, B1r, B1i;
    if ((j & 1) == 0) {        // 'a': e1*(c1*a - s1*b)
        float er = cosf(ph1), ei = sinf(ph1);
        A1r = er * c1; A1i = ei * c1;
        B1r = -er * s1; B1i = -ei * s1;
    } else {                   // 'b': s1*a + c1*b
        A1r = c1; A1i = 0.f;
        B1r = s1; B1i = 0.f;
    }

    // ---- layer-2 (+omega): s = A2*t + BL*t[j+1] + BR*t[j-1], parity-folded ----
    float A2r, A2i, BLr, BLi, BRr, BRi;
    if (j == 0 || j == 63) {
        A2r = 1.f; A2i = 0.f; BLr = 0.f; BLi = 0.f; BRr = 0.f; BRi = 0.f;
    } else {
        int k2 = (j - 1) >> 1;
        float th2 = theta2[h * 31 + k2], ph2 = phi2[h * 31 + k2];
        float c2 = cosf(th2), s2 = sinf(th2);
        if (j & 1) {           // odd = 'a': e2*(c2*self - s2*next)
            float er = cosf(ph2), ei = sinf(ph2);
            A2r = er * c2; A2i = ei * c2;
            BLr = -er * s2; BLi = -ei * s2;
            BRr = 0.f; BRi = 0.f;
        } else {               // even = 'b': s2*prev + c2*self
            A2r = c2; A2i = 0.f;
            BRr = s2; BRi = 0.f;
            BLr = 0.f; BLi = 0.f;
        }
    }
    {   // fold exp(i*omega) into A2, BL, BR
        float om = omega[h * 64 + j];
        float eor = cosf(om), eoi = sinf(om);
        float tr, ti;
        tr = A2r * eor - A2i * eoi; ti = A2r * eoi + A2i * eor; A2r = tr; A2i = ti;
        tr = BLr * eor - BLi * eoi; ti = BLr * eoi + BLi * eor; BLr = tr; BLi = ti;
        tr = BRr * eor - BRi * eoi; ti = BRr * eoi + BRi * eor; BRr = tr; BRi = ti;
    }
    float bj = bias[h * 64 + j];

    // ---- Aq for both rows (packed); query rows block-uniform -> s_load ----
    const float* qrow0 = queries + n0 * DIM;
    const float* qrow1 = queries + n1 * DIM;
    const float* ur = U_re + (h * 2 * DIM) * DIM + j;
    const float* ui = U_im + (h * 2 * DIM) * DIM + j;
    f2 Uqr = 0.f, Uqi = 0.f;   // component 0 = row n0, 1 = row n1
    #pragma unroll 8
    for (int i = 0; i < DIM; ++i) {
        f2 a; a.x = qrow0[i]; a.y = qrow1[i];
        float wr = ur[i * DIM], wi = ui[i * DIM];
        Uqr += a * wr;
        Uqi += a * wi;
    }

    const f2* Avp = Av + (h * 1024 + b * 128) * DIM + j;

    f2 Hr = 0.f, Hi = 0.f;
    f2 av = Avp[0];
    f2 uvr = Uqr + av.x, uvi = Uqi + av.y;   // input term for step 0, off-chain
    #pragma unroll 4
    for (int v = 0; v < VV; ++v) {
        f2 avn = Avp[((v + 1) & 127) * DIM];   // prefetch next (wrap: unused)
        // layer 1
        f2 Pr = dpp2_swap1(Hr), Pi = dpp2_swap1(Hi);
        f2 Tr = (A1r * Hr - A1i * Hi) + (B1r * Pr - B1i * Pi);
        f2 Ti = (A1r * Hi + A1i * Hr) + (B1r * Pi + B1i * Pr);
        // layer 2 (+omega)
        f2 Lr = dpp2_shl1(Tr), Li = dpp2_shl1(Ti);
        f2 Rr = dpp2_shr1(Tr), Ri = dpp2_shr1(Ti);
        f2 Sr = (A2r * Tr - A2i * Ti) + (BLr * Lr - BLi * Li) + (BRr * Rr - BRi * Ri);
        f2 Si = (A2r * Ti + A2i * Tr) + (BLr * Li + BLi * Lr) + (BRr * Ri + BRi * Rr);
        // input: u = Aq + Av[v] (precomputed off the dependency chain)
        f2 Zr = Sr + uvr;
        f2 Zi = Si + uvi;
        // next step's input term — depends only on the prefetched load
        uvr = Uqr + avn.x; uvi = Uqi + avn.y;
        // modrelu: m = sqrt(q2), 1/m == rs; sc = relu(m + b) * rs
        f2 q2 = Zr * Zr + Zi * Zi + 1e-10f;    // m >= 1e-5, matches ref's eps scale
        f2 rs; rs.x = __builtin_amdgcn_rsqf(q2.x); rs.y = __builtin_amdgcn_rsqf(q2.y);
        f2 tp = q2 * rs + bj;                  // fma: m + b
        tp.x = fmaxf(tp.x, 0.f); tp.y = fmaxf(tp.y, 0.f);
        f2 sc = tp * rs;
        Hr = Zr * sc; Hi = Zi * sc;
        av = avn;
    }

    // ---- fused dense for rows n0, n1 ----
    __shared__ float s_acc[2][HEADS * DIM];   // 2 x 256
    __shared__ float s_part[256];
    s_acc[0][h * 64 + j] = Hr.x;
    s_acc[1][h * 64 + j] = Hr.y;
    __syncthreads();

    {   // thread t: row r = t>>7, k-half hf = (t>>6)&1, col jj = t&63
        int r = t >> 7, hf = (t >> 6) & 1, jj = t & 63;
        const float* Wp = W_dense + (hf * 128) * DIM + jj;
        const float* ap = &s_acc[r][hf * 128];
        float part = 0.f;
        #pragma unroll 8
        for (int k = 0; k < 128; ++k)
            part = fmaf(ap[k], Wp[k * DIM], part);   // ap broadcast, Wp coalesced
        s_part[t] = part;
    }
    __syncthreads();
    if (t < 128) {
        int r = t >> 6, jj = t & 63;
        y[(n0 + r * 64) * DIM + jj] =
            b_dense[jj] + s_part[r * 128 + jj] + s_part[r * 128 + 64 + jj];
    }
}

extern "C" void kernel_launch(void* const* d_in, const int* in_sizes, int n_in,
                              void* d_out, int out_size, void* d_ws, size_t ws_size,
                              hipStream_t stream) {
    const float* queries = (const float*)d_in[0];
    const float* values  = (const float*)d_in[1];
    const float* U_re    = (const float*)d_in[2];
    const float* U_im    = (const float*)d_in[3];
    const float* bias    = (const float*)d_in[4];
    const float* theta1  = (const float*)d_in[5];
    const float* phi1    = (const float*)d_in[6];
    const float* theta2  = (const float*)d_in[7];
    const float* phi2    = (const float*)d_in[8];
    const float* omega   = (const float*)d_in[9];
    const float* W_dense = (const float*)d_in[10];
    const float* b_dense = (const float*)d_in[11];
    float* y = (float*)d_out;

    f2* Av = (f2*)d_ws;   // HEADS*1024*64 f2 = 2 MB

    k_av<<<256, 256, 0, stream>>>(values, U_re, U_im, Av);
    k_rnn_dense<<<512, 256, 0, stream>>>(queries, U_re, U_im, bias, theta1,
                                         phi1, theta2, phi2, omega, Av,
                                         W_dense, b_dense, y);
}